// Round 4
// baseline (6217.594 us; speedup 1.0000x reference)
//
#include <hip/hip_runtime.h>
#include <hip/hip_bf16.h>
#include <stdint.h>

#define LATENT 256
#define HIDDEN 1024
#define GOUT 512
#define NB 32
#define TT 512
#define G3 1536

typedef float f32x4 __attribute__((ext_vector_type(4)));
typedef short s16x8 __attribute__((ext_vector_type(8)));
typedef uint32_t u32;
typedef unsigned long long u64;

#define GLP(p) ((const __attribute__((address_space(1))) u32*)(p))
#define LLP(p) ((__attribute__((address_space(3))) u32*)(p))

__device__ __forceinline__ short f2bf(float f) {
  u32 u = __builtin_bit_cast(u32, f);
  u32 r = (u + 0x7FFFu + ((u >> 16) & 1u)) >> 16;
  return (short)r;
}
__device__ __forceinline__ float bf2f(short s) {
  u32 u = ((u32)(unsigned short)s) << 16;
  return __builtin_bit_cast(float, u);
}
__device__ __forceinline__ u32 pk2(float a, float b) {
  return (u32)(unsigned short)f2bf(a) | ((u32)(unsigned short)f2bf(b) << 16);
}
__device__ __forceinline__ s16x8 f2bf8(float4 a, float4 b) {
  s16x8 r;
  r[0] = f2bf(a.x); r[1] = f2bf(a.y); r[2] = f2bf(a.z); r[3] = f2bf(a.w);
  r[4] = f2bf(b.x); r[5] = f2bf(b.y); r[6] = f2bf(b.z); r[7] = f2bf(b.w);
  return r;
}
__device__ __forceinline__ float ldgx(const float* p) { return *p; }
__device__ __forceinline__ float ldgx(const short* p) { return bf2f(*p); }

// ---------------- fc + relu ----------------
__global__ __launch_bounds__(256) void fc_kernel(const float* __restrict__ z,
                                                 const float* __restrict__ fc_w,
                                                 const float* __restrict__ fc_b,
                                                 float* __restrict__ hfc) {
  __shared__ float zs[LATENT];
  int tid = threadIdx.x;
  int gid = blockIdx.x * 256 + tid;
  int b = gid >> 10, j = gid & 1023;
  zs[tid] = z[b * LATENT + tid];
  __syncthreads();
  const float4* wr = (const float4*)(fc_w + (size_t)j * LATENT);
  float s = 0.f;
#pragma unroll
  for (int k = 0; k < LATENT / 4; ++k) {
    float4 wv = wr[k];
    float4 zv = *(const float4*)&zs[k * 4];
    s += wv.x * zv.x + wv.y * zv.y + wv.z * zv.z + wv.w * zv.w;
  }
  s += fc_b[j];
  hfc[gid] = fmaxf(s, 0.f);
}

// ------------- x0[t][b][k] = bf16(hfc[b][k] + chord[b][t][k]/100) -------------
__global__ __launch_bounds__(256) void x0_kernel(const float* __restrict__ hfc,
                                                 const float* __restrict__ chord,
                                                 short* __restrict__ x0) {
  int r = blockIdx.x;          // r = t*32 + b
  int b = r & 31, t = r >> 5;
  int k = threadIdx.x * 4;
  float4 c = *(const float4*)(chord + ((size_t)b * TT + t) * HIDDEN + k);
  float4 h = *(const float4*)(hfc + (size_t)b * HIDDEN + k);
  u32 p0 = pk2(h.x + c.x * 0.01f, h.y + c.y * 0.01f);
  u32 p1 = pk2(h.z + c.z * 0.01f, h.w + c.w * 0.01f);
  uint2 pv; pv.x = p0; pv.y = p1;
  *(uint2*)(x0 + (size_t)r * HIDDEN + k) = pv;
}

// ---------------- fp32 -> bf16 weight convert ----------------
__global__ __launch_bounds__(256) void cvt_kernel(const float* __restrict__ src,
                                                  short* __restrict__ dst, int n4) {
  int i = blockIdx.x * 256 + threadIdx.x;
  if (i < n4) {
    float4 v = ((const float4*)src)[i];
    uint2 pv; pv.x = pk2(v.x, v.y); pv.y = pk2(v.z, v.w);
    ((uint2*)dst)[i] = pv;
  }
}

// ---------------- GEMM: C[M][N] = A[M][K](bf16) @ Bw[N][K]^T(bf16) ----------------
template <typename OutT>
__global__ __launch_bounds__(256) void gemm_bt(const short* __restrict__ A,
                                               const short* __restrict__ Bw,
                                               OutT* __restrict__ C, int M, int N, int K) {
  __shared__ short As[128 * 32];
  __shared__ short Bs[128 * 32];
  const int tid = threadIdx.x;
  const int lane = tid & 63, wave = tid >> 6;
  const int l15 = lane & 15, quad = lane >> 4;
  const int n0 = blockIdx.x * 128, m0 = blockIdx.y * 128;
  const int wm = (wave >> 1) * 64, wn = (wave & 1) * 64;
  f32x4 acc[4][4] = {};
  for (int k0 = 0; k0 < K; k0 += 32) {
#pragma unroll
    for (int c = 0; c < 2; ++c) {
      int idx = c * 256 + tid;
      int row = idx >> 2, cs = (idx & 3) * 8;
      const u32* ga = (const u32*)(A + (size_t)(m0 + row) * K + k0 + cs);
      const u32* gb = (const u32*)(Bw + (size_t)(n0 + row) * K + k0 + cs);
      u32* sa = (u32*)As + (size_t)(c * 256 + wave * 64) * 4;
      u32* sb = (u32*)Bs + (size_t)(c * 256 + wave * 64) * 4;
      __builtin_amdgcn_global_load_lds(GLP(ga), LLP(sa), 16, 0, 0);
      __builtin_amdgcn_global_load_lds(GLP(gb), LLP(sb), 16, 0, 0);
    }
    __syncthreads();
    s16x8 af[4], bfr[4];
#pragma unroll
    for (int i = 0; i < 4; ++i)
      af[i] = *(const s16x8*)(As + (wm + i * 16 + l15) * 32 + quad * 8);
#pragma unroll
    for (int j = 0; j < 4; ++j)
      bfr[j] = *(const s16x8*)(Bs + (wn + j * 16 + l15) * 32 + quad * 8);
#pragma unroll
    for (int i = 0; i < 4; ++i)
#pragma unroll
      for (int j = 0; j < 4; ++j)
        acc[i][j] = __builtin_amdgcn_mfma_f32_16x16x32_bf16(af[i], bfr[j], acc[i][j], 0, 0, 0);
    __syncthreads();
  }
#pragma unroll
  for (int i = 0; i < 4; ++i)
#pragma unroll
    for (int j = 0; j < 4; ++j)
#pragma unroll
      for (int r = 0; r < 4; ++r) {
        int m = m0 + wm + i * 16 + quad * 4 + r;
        int n = n0 + wn + j * 16 + l15;
        float v = acc[i][j][r];
        if constexpr (__is_same(OutT, float)) C[(size_t)m * N + n] = v;
        else C[(size_t)m * N + n] = f2bf(v);
      }
}

// ---------------- persistent GRU layer (v2 topology) ----------------
// 2 groups x 16 batches; 32 WGs/group x 16 units; 256 thr = 4 waves.
// Waves 0-2: gate r/z/n MFMA (M=16 real batches, zero A duplication).
// h exchange: tagged u64 {tag|2xbf16}, relaxed agent atomics, double buffer.
// h staged into LDS with XOR swizzle: word c of row r at r*256 + (c^((r&7)*4))
// -> A-frag b128 reads hit all 32 banks (8 words/bank physical floor).
// Combine: 1 (batch,unit) per thread; h_prev stays in that thread's register.
template <typename GxT>
__global__ __launch_bounds__(256) void gru_layer(const GxT* __restrict__ gx,       // [T][32][1536]
                                                 const float* __restrict__ w_hh,   // [1536][512]
                                                 const float* __restrict__ b_ih,
                                                 const float* __restrict__ b_hh,
                                                 u64* __restrict__ h_buf,          // [2 grp][2 buf][16][256] u64
                                                 int tag_base,
                                                 short* __restrict__ x_out,        // [T][32][512] bf16 or null
                                                 float* __restrict__ f_out,        // [32][T][512] fp32 or null
                                                 const int* __restrict__ seq_lens) {
  const int bid = blockIdx.x;                 // 64 WGs
  const int gI = bid & 1, wg = bid >> 1;      // 2 groups x 32 WGs
  const int u0 = wg * 16;
  const int tid = threadIdx.x, lane = tid & 63, wave = tid >> 6;
  const int l15 = lane & 15, quad = lane >> 4;
  __shared__ u32 h_lds[16 * 256];             // swizzled payload
  __shared__ float lds_c[3 * 16 * 16];        // [gate][batch][unit]

  u64* hb = h_buf + (size_t)gI * 8192;        // 2 bufs x 4096 words

  // --- persistent w_hh fragments for gate waves (bf16, 64 VGPRs) ---
  s16x8 wfrag[16];
  if (wave < 3) {
    const int col = wave * 512 + u0 + l15;
#pragma unroll
    for (int kb = 0; kb < 16; ++kb) {
      const float* p = w_hh + (size_t)col * 512 + kb * 32 + quad * 8;
      wfrag[kb] = f2bf8(*(const float4*)p, *(const float4*)(p + 4));
    }
  }

  // --- combine mapping: thread -> (batch cb, unit u0+cu) ---
  const int cb = tid >> 4, cu = tid & 15;
  const int gb = gI * 16 + cb;                // global batch
  const int u = u0 + cu;
  const float bihr = b_ih[u], bihz = b_ih[512 + u], bihn = b_ih[1024 + u];
  const float bhhr = b_hh[u], bhhz = b_hh[512 + u], bhhn = b_hh[1024 + u];
  const int slen = seq_lens[gb];
  float hprev = 0.f;

  // --- staging mapping: thread covers rows wave*4..+3, words swb..swb+3 ---
  const int swb = (lane) * 4;                 // u64 word idx within row
  const int srow0 = wave * 4;

  float pgx[3];
#pragma unroll
  for (int g = 0; g < 3; ++g)
    pgx[g] = ldgx(&gx[(size_t)gb * G3 + g * 512 + u]);

  for (int t = 0; t < TT; ++t) {
    // ---- poll h[t-1] tagged words, stage payload into swizzled LDS ----
    if (t > 0) {
      const u32 want = (u32)(tag_base + t);
      u64* src = hb + ((t - 1) & 1) * 4096;
      u64 v[16];
#pragma unroll
      for (int i = 0; i < 4; ++i)
#pragma unroll
        for (int j = 0; j < 4; ++j)
          v[i * 4 + j] = __hip_atomic_load(src + (srow0 + i) * 256 + swb + j,
                                           __ATOMIC_RELAXED, __HIP_MEMORY_SCOPE_AGENT);
#pragma unroll
      for (int i = 0; i < 4; ++i)
#pragma unroll
        for (int j = 0; j < 4; ++j) {
          while ((u32)(v[i * 4 + j] >> 32) != want)
            v[i * 4 + j] = __hip_atomic_load(src + (srow0 + i) * 256 + swb + j,
                                             __ATOMIC_RELAXED, __HIP_MEMORY_SCOPE_AGENT);
        }
#pragma unroll
      for (int i = 0; i < 4; ++i) {
        const int row = srow0 + i;
        uint4 pw;
        pw.x = (u32)v[i * 4 + 0]; pw.y = (u32)v[i * 4 + 1];
        pw.z = (u32)v[i * 4 + 2]; pw.w = (u32)v[i * 4 + 3];
        *(uint4*)&h_lds[row * 256 + (swb ^ ((row & 7) * 4))] = pw;
      }
    }
    __syncthreads();

    // ---- gate MFMA (waves 0-2): gh tile 16 batches x 16 units ----
    f32x4 a0 = {0.f, 0.f, 0.f, 0.f}, a1 = a0, a2 = a0, a3 = a0;
    if (wave < 3 && t > 0) {
#pragma unroll
      for (int kb = 0; kb < 16; ++kb) {
        s16x8 a = *(const s16x8*)&h_lds[l15 * 256 + ((kb * 16 + quad * 4) ^ ((l15 & 7) * 4))];
        if ((kb & 3) == 0)      a0 = __builtin_amdgcn_mfma_f32_16x16x32_bf16(a, wfrag[kb], a0, 0, 0, 0);
        else if ((kb & 3) == 1) a1 = __builtin_amdgcn_mfma_f32_16x16x32_bf16(a, wfrag[kb], a1, 0, 0, 0);
        else if ((kb & 3) == 2) a2 = __builtin_amdgcn_mfma_f32_16x16x32_bf16(a, wfrag[kb], a2, 0, 0, 0);
        else                    a3 = __builtin_amdgcn_mfma_f32_16x16x32_bf16(a, wfrag[kb], a3, 0, 0, 0);
      }
    }
    if (wave < 3) {
      f32x4 acc;
#pragma unroll
      for (int r = 0; r < 4; ++r) acc[r] = (a0[r] + a1[r]) + (a2[r] + a3[r]);
#pragma unroll
      for (int r = 0; r < 4; ++r)
        lds_c[wave * 256 + (quad * 4 + r) * 16 + l15] = acc[r];
    }
    __syncthreads();

    // ---- combine: all 256 threads, one (batch, unit) each ----
    {
      float ghr = lds_c[0 * 256 + cb * 16 + cu];
      float ghz = lds_c[1 * 256 + cb * 16 + cu];
      float ghn = lds_c[2 * 256 + cb * 16 + cu];
      float cr = pgx[0], cz = pgx[1], cn = pgx[2];
      if (t + 1 < TT) {
#pragma unroll
        for (int g = 0; g < 3; ++g)
          pgx[g] = ldgx(&gx[(size_t)((t + 1) * NB + gb) * G3 + g * 512 + u]);
      }
      float xr = cr + bihr + ghr + bhhr;
      float xz = cz + bihz + ghz + bhhz;
      float rr = 1.f / (1.f + __expf(-xr));
      float zz = 1.f / (1.f + __expf(-xz));
      float pre = cn + bihn + rr * (ghn + bhhn);
      float ax = fabsf(pre);
      float e = __expf(-2.f * ax);
      float nn = copysignf((1.f - e) / (1.f + e), pre);
      float h = (1.f - zz) * nn + zz * hprev;
      hprev = h;
      float other = __shfl_xor(h, 1);
      if (!(tid & 1)) {
        u64 val = (u64)pk2(h, other) | (((u64)(u32)(tag_base + t + 1)) << 32);
        __hip_atomic_store(hb + (t & 1) * 4096 + cb * 256 + (u >> 1), val,
                           __ATOMIC_RELAXED, __HIP_MEMORY_SCOPE_AGENT);
      }
      if (x_out) x_out[(size_t)(t * NB + gb) * 512 + u] = f2bf(h);
      if (f_out) f_out[((size_t)gb * TT + t) * 512 + u] = (t < slen) ? h : 0.f;
    }
  }
}

extern "C" void kernel_launch(void* const* d_in, const int* in_sizes, int n_in,
                              void* d_out, int out_size, void* d_ws, size_t ws_size,
                              hipStream_t stream) {
  (void)in_sizes; (void)n_in; (void)out_size;
  const float* z       = (const float*)d_in[0];
  const int*   seq     = (const int*)d_in[1];
  const float* chord   = (const float*)d_in[2];
  const float* fc_w    = (const float*)d_in[3];
  const float* fc_b    = (const float*)d_in[4];
  const float* w_ih[3] = {(const float*)d_in[5], (const float*)d_in[9],  (const float*)d_in[13]};
  const float* w_hh[3] = {(const float*)d_in[6], (const float*)d_in[10], (const float*)d_in[14]};
  const float* b_ih[3] = {(const float*)d_in[7], (const float*)d_in[11], (const float*)d_in[15]};
  const float* b_hh[3] = {(const float*)d_in[8], (const float*)d_in[12], (const float*)d_in[16]};

  char* w = (char*)d_ws;
  size_t off = 0;
  auto alloc = [&](size_t bytes) -> void* {
    void* p = w + off;
    off = (off + bytes + 255) & ~(size_t)255;
    return p;
  };
  u64*   hbuf = (u64*)alloc((size_t)2 * 8192 * 8);           // tagged h words
  float* hfc  = (float*)alloc((size_t)NB * HIDDEN * 4);
  short* x0   = (short*)alloc((size_t)TT * NB * HIDDEN * 2);
  short* x1   = (short*)alloc((size_t)TT * NB * GOUT * 2);   // reused as x2
  short* w0b  = (short*)alloc((size_t)G3 * HIDDEN * 2);
  short* w1b  = (short*)alloc((size_t)G3 * GOUT * 2);
  short* w2b  = (short*)alloc((size_t)G3 * GOUT * 2);
  size_t fixed = off;
  bool gx_f32 = (fixed + (size_t)TT * NB * G3 * 4) <= ws_size;
  void* gx = alloc(gx_f32 ? (size_t)TT * NB * G3 * 4 : (size_t)TT * NB * G3 * 2);

  fc_kernel<<<128, 256, 0, stream>>>(z, fc_w, fc_b, hfc);
  x0_kernel<<<TT * NB, 256, 0, stream>>>(hfc, chord, x0);
  cvt_kernel<<<(G3 * HIDDEN / 4 + 255) / 256, 256, 0, stream>>>(w_ih[0], w0b, G3 * HIDDEN / 4);
  cvt_kernel<<<(G3 * GOUT / 4 + 255) / 256, 256, 0, stream>>>(w_ih[1], w1b, G3 * GOUT / 4);
  cvt_kernel<<<(G3 * GOUT / 4 + 255) / 256, 256, 0, stream>>>(w_ih[2], w2b, G3 * GOUT / 4);

  dim3 gg(G3 / 128, TT * NB / 128);
  if (gx_f32) {
    float* gxf = (float*)gx;
    gemm_bt<float><<<gg, 256, 0, stream>>>(x0, w0b, gxf, TT * NB, G3, HIDDEN);
    gru_layer<float><<<64, 256, 0, stream>>>(gxf, w_hh[0], b_ih[0], b_hh[0], hbuf, 0 * 1024, x1, nullptr, seq);
    gemm_bt<float><<<gg, 256, 0, stream>>>(x1, w1b, gxf, TT * NB, G3, GOUT);
    gru_layer<float><<<64, 256, 0, stream>>>(gxf, w_hh[1], b_ih[1], b_hh[1], hbuf, 1 * 1024, x1, nullptr, seq);
    gemm_bt<float><<<gg, 256, 0, stream>>>(x1, w2b, gxf, TT * NB, G3, GOUT);
    gru_layer<float><<<64, 256, 0, stream>>>(gxf, w_hh[2], b_ih[2], b_hh[2], hbuf, 2 * 1024, nullptr, (float*)d_out, seq);
  } else {
    short* gxb = (short*)gx;
    gemm_bt<short><<<gg, 256, 0, stream>>>(x0, w0b, gxb, TT * NB, G3, HIDDEN);
    gru_layer<short><<<64, 256, 0, stream>>>(gxb, w_hh[0], b_ih[0], b_hh[0], hbuf, 0 * 1024, x1, nullptr, seq);
    gemm_bt<short><<<gg, 256, 0, stream>>>(x1, w1b, gxb, TT * NB, G3, GOUT);
    gru_layer<short><<<64, 256, 0, stream>>>(gxb, w_hh[1], b_ih[1], b_hh[1], hbuf, 1 * 1024, x1, nullptr, seq);
    gemm_bt<short><<<gg, 256, 0, stream>>>(x1, w2b, gxb, TT * NB, G3, GOUT);
    gru_layer<short><<<64, 256, 0, stream>>>(gxb, w_hh[2], b_ih[2], b_hh[2], hbuf, 2 * 1024, nullptr, (float*)d_out, seq);
  }
}

// Round 5
// 2685.504 us; speedup vs baseline: 2.3152x; 2.3152x over previous
//
#include <hip/hip_runtime.h>
#include <hip/hip_bf16.h>
#include <stdint.h>

#define LATENT 256
#define HIDDEN 1024
#define GOUT 512
#define NB 32
#define TT 512
#define G3 1536

typedef float f32x4 __attribute__((ext_vector_type(4)));
typedef short s16x8 __attribute__((ext_vector_type(8)));
typedef uint32_t u32;
typedef unsigned long long u64;

#define GLP(p) ((const __attribute__((address_space(1))) u32*)(p))
#define LLP(p) ((__attribute__((address_space(3))) u32*)(p))

__device__ __forceinline__ short f2bf(float f) {
  u32 u = __builtin_bit_cast(u32, f);
  u32 r = (u + 0x7FFFu + ((u >> 16) & 1u)) >> 16;
  return (short)r;
}
__device__ __forceinline__ float bf2f(short s) {
  u32 u = ((u32)(unsigned short)s) << 16;
  return __builtin_bit_cast(float, u);
}
__device__ __forceinline__ u32 pk2(float a, float b) {
  return (u32)(unsigned short)f2bf(a) | ((u32)(unsigned short)f2bf(b) << 16);
}
__device__ __forceinline__ s16x8 f2bf8(float4 a, float4 b) {
  s16x8 r;
  r[0] = f2bf(a.x); r[1] = f2bf(a.y); r[2] = f2bf(a.z); r[3] = f2bf(a.w);
  r[4] = f2bf(b.x); r[5] = f2bf(b.y); r[6] = f2bf(b.z); r[7] = f2bf(b.w);
  return r;
}
__device__ __forceinline__ float ldgx(const float* p) { return *p; }
__device__ __forceinline__ float ldgx(const short* p) { return bf2f(*p); }

// ---------------- fc + relu ----------------
__global__ __launch_bounds__(256) void fc_kernel(const float* __restrict__ z,
                                                 const float* __restrict__ fc_w,
                                                 const float* __restrict__ fc_b,
                                                 float* __restrict__ hfc) {
  __shared__ float zs[LATENT];
  int tid = threadIdx.x;
  int gid = blockIdx.x * 256 + tid;
  int b = gid >> 10, j = gid & 1023;
  zs[tid] = z[b * LATENT + tid];
  __syncthreads();
  const float4* wr = (const float4*)(fc_w + (size_t)j * LATENT);
  float s = 0.f;
#pragma unroll
  for (int k = 0; k < LATENT / 4; ++k) {
    float4 wv = wr[k];
    float4 zv = *(const float4*)&zs[k * 4];
    s += wv.x * zv.x + wv.y * zv.y + wv.z * zv.z + wv.w * zv.w;
  }
  s += fc_b[j];
  hfc[gid] = fmaxf(s, 0.f);
}

// ------------- x0[t][b][k] = bf16(hfc[b][k] + chord[b][t][k]/100) -------------
__global__ __launch_bounds__(256) void x0_kernel(const float* __restrict__ hfc,
                                                 const float* __restrict__ chord,
                                                 short* __restrict__ x0) {
  int r = blockIdx.x;          // r = t*32 + b
  int b = r & 31, t = r >> 5;
  int k = threadIdx.x * 4;
  float4 c = *(const float4*)(chord + ((size_t)b * TT + t) * HIDDEN + k);
  float4 h = *(const float4*)(hfc + (size_t)b * HIDDEN + k);
  u32 p0 = pk2(h.x + c.x * 0.01f, h.y + c.y * 0.01f);
  u32 p1 = pk2(h.z + c.z * 0.01f, h.w + c.w * 0.01f);
  uint2 pv; pv.x = p0; pv.y = p1;
  *(uint2*)(x0 + (size_t)r * HIDDEN + k) = pv;
}

// ---------------- fp32 -> bf16 weight convert ----------------
__global__ __launch_bounds__(256) void cvt_kernel(const float* __restrict__ src,
                                                  short* __restrict__ dst, int n4) {
  int i = blockIdx.x * 256 + threadIdx.x;
  if (i < n4) {
    float4 v = ((const float4*)src)[i];
    uint2 pv; pv.x = pk2(v.x, v.y); pv.y = pk2(v.z, v.w);
    ((uint2*)dst)[i] = pv;
  }
}

// ---------------- GEMM: C[M][N] = A[M][K](bf16) @ Bw[N][K]^T(bf16) ----------------
template <typename OutT>
__global__ __launch_bounds__(256) void gemm_bt(const short* __restrict__ A,
                                               const short* __restrict__ Bw,
                                               OutT* __restrict__ C, int M, int N, int K) {
  __shared__ short As[128 * 32];
  __shared__ short Bs[128 * 32];
  const int tid = threadIdx.x;
  const int lane = tid & 63, wave = tid >> 6;
  const int l15 = lane & 15, quad = lane >> 4;
  const int n0 = blockIdx.x * 128, m0 = blockIdx.y * 128;
  const int wm = (wave >> 1) * 64, wn = (wave & 1) * 64;
  f32x4 acc[4][4] = {};
  for (int k0 = 0; k0 < K; k0 += 32) {
#pragma unroll
    for (int c = 0; c < 2; ++c) {
      int idx = c * 256 + tid;
      int row = idx >> 2, cs = (idx & 3) * 8;
      const u32* ga = (const u32*)(A + (size_t)(m0 + row) * K + k0 + cs);
      const u32* gb = (const u32*)(Bw + (size_t)(n0 + row) * K + k0 + cs);
      u32* sa = (u32*)As + (size_t)(c * 256 + wave * 64) * 4;
      u32* sb = (u32*)Bs + (size_t)(c * 256 + wave * 64) * 4;
      __builtin_amdgcn_global_load_lds(GLP(ga), LLP(sa), 16, 0, 0);
      __builtin_amdgcn_global_load_lds(GLP(gb), LLP(sb), 16, 0, 0);
    }
    __syncthreads();
    s16x8 af[4], bfr[4];
#pragma unroll
    for (int i = 0; i < 4; ++i)
      af[i] = *(const s16x8*)(As + (wm + i * 16 + l15) * 32 + quad * 8);
#pragma unroll
    for (int j = 0; j < 4; ++j)
      bfr[j] = *(const s16x8*)(Bs + (wn + j * 16 + l15) * 32 + quad * 8);
#pragma unroll
    for (int i = 0; i < 4; ++i)
#pragma unroll
      for (int j = 0; j < 4; ++j)
        acc[i][j] = __builtin_amdgcn_mfma_f32_16x16x32_bf16(af[i], bfr[j], acc[i][j], 0, 0, 0);
    __syncthreads();
  }
#pragma unroll
  for (int i = 0; i < 4; ++i)
#pragma unroll
    for (int j = 0; j < 4; ++j)
#pragma unroll
      for (int r = 0; r < 4; ++r) {
        int m = m0 + wm + i * 16 + quad * 4 + r;
        int n = n0 + wn + j * 16 + l15;
        float v = acc[i][j][r];
        if constexpr (__is_same(OutT, float)) C[(size_t)m * N + n] = v;
        else C[(size_t)m * N + n] = f2bf(v);
      }
}

// ---------------- persistent GRU layer (v3) ----------------
// 8 groups x 4 batches; 16 WGs/group x 32 units; 512 thr = 8 waves.
//   waves 0-5: gate (r/z/n) x half MFMA, w_hh B-frags persistent in VGPRs.
//   waves 6-7: combine (1 (batch,unit) per thread), tagged h stores, outputs,
//              gx prefetch — transcendentals off the MFMA waves.
// All 8 waves poll exactly 2 tagged u64 words each (1024 total = group h).
// h_lds XOR swizzle addr(r,c) = r*256 + (c ^ r*4 ^ (r&1)*16):
//   A-frag b128 reads -> 2 addrs/bank (free, m136); b64 stage writes stay
//   contiguous. Tag t+1 into buf[t&1]; skew>1 impossible (producer needs all
//   step-t stores before step t+1).
template <typename GxT>
__global__ __launch_bounds__(512) void gru_layer(const GxT* __restrict__ gx,       // [T][32][1536]
                                                 const float* __restrict__ w_hh,   // [1536][512]
                                                 const float* __restrict__ b_ih,
                                                 const float* __restrict__ b_hh,
                                                 u64* __restrict__ h_buf,          // [8 grp][2 buf][4][256] u64
                                                 int tag_base,
                                                 short* __restrict__ x_out,        // [T][32][512] bf16 or null
                                                 float* __restrict__ f_out,        // [32][T][512] fp32 or null
                                                 const int* __restrict__ seq_lens) {
  const int bid = blockIdx.x;                 // 128 WGs
  const int g = bid & 7, wg = bid >> 3;       // 8 groups x 16 WGs
  const int u0 = wg * 32;
  const int tid = threadIdx.x, lane = tid & 63, wave = tid >> 6;
  const int l15 = lane & 15, quad = lane >> 4;
  __shared__ u32 h_lds[4 * 256];              // swizzled h payload (4 rows x 512 units)
  __shared__ float lds_c[3 * 4 * 32];         // [gate][batch][unit]

  u64* hb = h_buf + (size_t)g * 2048;

  // --- persistent w_hh B-fragments for gate waves ---
  const int gate = wave >> 1, half = wave & 1;
  s16x8 wfrag[16];
  if (wave < 6) {
    const int col = gate * 512 + u0 + half * 16 + l15;
#pragma unroll
    for (int kb = 0; kb < 16; ++kb) {
      const float* p = w_hh + (size_t)col * 512 + kb * 32 + quad * 8;
      wfrag[kb] = f2bf8(*(const float4*)p, *(const float4*)(p + 4));
    }
  }

  // --- combine threads (waves 6-7): one (batch, unit) each ---
  const bool is_c = (wave >= 6);
  const int ci = tid - 384;                   // 0..127
  const int cb = ci >> 5, cu = ci & 31;
  const int gbat = g * 4 + cb, u = u0 + cu;
  float bihr = 0, bihz = 0, bihn = 0, bhhr = 0, bhhz = 0, bhhn = 0;
  int slen = 0;
  float hprev = 0.f, pgx[3] = {0.f, 0.f, 0.f};
  if (is_c) {
    bihr = b_ih[u]; bihz = b_ih[512 + u]; bihn = b_ih[1024 + u];
    bhhr = b_hh[u]; bhhz = b_hh[512 + u]; bhhn = b_hh[1024 + u];
    slen = seq_lens[gbat];
#pragma unroll
    for (int gs = 0; gs < 3; ++gs)
      pgx[gs] = ldgx(&gx[(size_t)gbat * G3 + gs * 512 + u]);
  }

  // --- poll/stage mapping: thread owns words 2*tid, 2*tid+1 (same row) ---
  const int w0 = tid * 2;
  const int srow = w0 >> 8, sc = w0 & 255;
  const int saddr = srow * 256 + (sc ^ (srow * 4) ^ ((srow & 1) * 16));

  for (int t = 0; t < TT; ++t) {
    if (t > 0) {
      const u32 want = (u32)(tag_base + t);
      u64* src = hb + ((t - 1) & 1) * 1024;
      u64 v0 = __hip_atomic_load(src + w0, __ATOMIC_RELAXED, __HIP_MEMORY_SCOPE_AGENT);
      u64 v1 = __hip_atomic_load(src + w0 + 1, __ATOMIC_RELAXED, __HIP_MEMORY_SCOPE_AGENT);
      while ((u32)(v0 >> 32) != want)
        v0 = __hip_atomic_load(src + w0, __ATOMIC_RELAXED, __HIP_MEMORY_SCOPE_AGENT);
      while ((u32)(v1 >> 32) != want)
        v1 = __hip_atomic_load(src + w0 + 1, __ATOMIC_RELAXED, __HIP_MEMORY_SCOPE_AGENT);
      uint2 pw; pw.x = (u32)v0; pw.y = (u32)v1;
      *(uint2*)&h_lds[saddr] = pw;
    }
    __syncthreads();

    // ---- gate MFMA (waves 0-5), 4 independent acc chains ----
    if (wave < 6) {
      f32x4 a0 = {0.f, 0.f, 0.f, 0.f}, a1 = a0, a2 = a0, a3 = a0;
      if (t > 0) {
        const int r = l15 & 3;
        const int rsw = r * 4, rhi = (r & 1) * 16;
#pragma unroll
        for (int kb = 0; kb < 16; ++kb) {
          s16x8 a = *(const s16x8*)&h_lds[r * 256 + ((kb * 16 + quad * 4) ^ rsw ^ rhi)];
          if ((kb & 3) == 0)      a0 = __builtin_amdgcn_mfma_f32_16x16x32_bf16(a, wfrag[kb], a0, 0, 0, 0);
          else if ((kb & 3) == 1) a1 = __builtin_amdgcn_mfma_f32_16x16x32_bf16(a, wfrag[kb], a1, 0, 0, 0);
          else if ((kb & 3) == 2) a2 = __builtin_amdgcn_mfma_f32_16x16x32_bf16(a, wfrag[kb], a2, 0, 0, 0);
          else                    a3 = __builtin_amdgcn_mfma_f32_16x16x32_bf16(a, wfrag[kb], a3, 0, 0, 0);
        }
      }
      if (quad == 0) {
        const int uc = half * 16 + l15;
#pragma unroll
        for (int r = 0; r < 4; ++r)
          lds_c[gate * 128 + r * 32 + uc] = (a0[r] + a1[r]) + (a2[r] + a3[r]);
      }
    }
    __syncthreads();

    // ---- combine (waves 6-7) ----
    if (is_c) {
      float ghr = lds_c[0 * 128 + cb * 32 + cu];
      float ghz = lds_c[1 * 128 + cb * 32 + cu];
      float ghn = lds_c[2 * 128 + cb * 32 + cu];
      float cr = pgx[0], cz = pgx[1], cn = pgx[2];
      if (t + 1 < TT) {
#pragma unroll
        for (int gs = 0; gs < 3; ++gs)
          pgx[gs] = ldgx(&gx[(size_t)((t + 1) * NB + gbat) * G3 + gs * 512 + u]);
      }
      float xr = cr + bihr + ghr + bhhr;
      float xz = cz + bihz + ghz + bhhz;
      float rr = 1.f / (1.f + __expf(-xr));
      float zz = 1.f / (1.f + __expf(-xz));
      float pre = cn + bihn + rr * (ghn + bhhn);
      float ax = fabsf(pre);
      float e = __expf(-2.f * ax);
      float nn = copysignf((1.f - e) / (1.f + e), pre);
      float h = (1.f - zz) * nn + zz * hprev;
      hprev = h;
      float other = __shfl_xor(h, 1);
      if (!(tid & 1)) {
        u64 val = (u64)pk2(h, other) | (((u64)(u32)(tag_base + t + 1)) << 32);
        __hip_atomic_store(hb + (t & 1) * 1024 + cb * 256 + (u >> 1), val,
                           __ATOMIC_RELAXED, __HIP_MEMORY_SCOPE_AGENT);
      }
      if (x_out) x_out[(size_t)(t * NB + gbat) * 512 + u] = f2bf(h);
      if (f_out) f_out[((size_t)gbat * TT + t) * 512 + u] = (t < slen) ? h : 0.f;
    }
  }
}

extern "C" void kernel_launch(void* const* d_in, const int* in_sizes, int n_in,
                              void* d_out, int out_size, void* d_ws, size_t ws_size,
                              hipStream_t stream) {
  (void)in_sizes; (void)n_in; (void)out_size;
  const float* z       = (const float*)d_in[0];
  const int*   seq     = (const int*)d_in[1];
  const float* chord   = (const float*)d_in[2];
  const float* fc_w    = (const float*)d_in[3];
  const float* fc_b    = (const float*)d_in[4];
  const float* w_ih[3] = {(const float*)d_in[5], (const float*)d_in[9],  (const float*)d_in[13]};
  const float* w_hh[3] = {(const float*)d_in[6], (const float*)d_in[10], (const float*)d_in[14]};
  const float* b_ih[3] = {(const float*)d_in[7], (const float*)d_in[11], (const float*)d_in[15]};
  const float* b_hh[3] = {(const float*)d_in[8], (const float*)d_in[12], (const float*)d_in[16]};

  char* w = (char*)d_ws;
  size_t off = 0;
  auto alloc = [&](size_t bytes) -> void* {
    void* p = w + off;
    off = (off + bytes + 255) & ~(size_t)255;
    return p;
  };
  u64*   hbuf = (u64*)alloc((size_t)8 * 2048 * 8);           // tagged h words
  float* hfc  = (float*)alloc((size_t)NB * HIDDEN * 4);
  short* x0   = (short*)alloc((size_t)TT * NB * HIDDEN * 2);
  short* x1   = (short*)alloc((size_t)TT * NB * GOUT * 2);   // reused as x2
  short* w0b  = (short*)alloc((size_t)G3 * HIDDEN * 2);
  short* w1b  = (short*)alloc((size_t)G3 * GOUT * 2);
  short* w2b  = (short*)alloc((size_t)G3 * GOUT * 2);
  size_t fixed = off;
  bool gx_f32 = (fixed + (size_t)TT * NB * G3 * 4) <= ws_size;
  void* gx = alloc(gx_f32 ? (size_t)TT * NB * G3 * 4 : (size_t)TT * NB * G3 * 2);

  fc_kernel<<<128, 256, 0, stream>>>(z, fc_w, fc_b, hfc);
  x0_kernel<<<TT * NB, 256, 0, stream>>>(hfc, chord, x0);
  cvt_kernel<<<(G3 * HIDDEN / 4 + 255) / 256, 256, 0, stream>>>(w_ih[0], w0b, G3 * HIDDEN / 4);
  cvt_kernel<<<(G3 * GOUT / 4 + 255) / 256, 256, 0, stream>>>(w_ih[1], w1b, G3 * GOUT / 4);
  cvt_kernel<<<(G3 * GOUT / 4 + 255) / 256, 256, 0, stream>>>(w_ih[2], w2b, G3 * GOUT / 4);

  dim3 gg(G3 / 128, TT * NB / 128);
  if (gx_f32) {
    float* gxf = (float*)gx;
    gemm_bt<float><<<gg, 256, 0, stream>>>(x0, w0b, gxf, TT * NB, G3, HIDDEN);
    gru_layer<float><<<128, 512, 0, stream>>>(gxf, w_hh[0], b_ih[0], b_hh[0], hbuf, 0 * 1024, x1, nullptr, seq);
    gemm_bt<float><<<gg, 256, 0, stream>>>(x1, w1b, gxf, TT * NB, G3, GOUT);
    gru_layer<float><<<128, 512, 0, stream>>>(gxf, w_hh[1], b_ih[1], b_hh[1], hbuf, 1 * 1024, x1, nullptr, seq);
    gemm_bt<float><<<gg, 256, 0, stream>>>(x1, w2b, gxf, TT * NB, G3, GOUT);
    gru_layer<float><<<128, 512, 0, stream>>>(gxf, w_hh[2], b_ih[2], b_hh[2], hbuf, 2 * 1024, nullptr, (float*)d_out, seq);
  } else {
    short* gxb = (short*)gx;
    gemm_bt<short><<<gg, 256, 0, stream>>>(x0, w0b, gxb, TT * NB, G3, HIDDEN);
    gru_layer<short><<<128, 512, 0, stream>>>(gxb, w_hh[0], b_ih[0], b_hh[0], hbuf, 0 * 1024, x1, nullptr, seq);
    gemm_bt<short><<<gg, 256, 0, stream>>>(x1, w1b, gxb, TT * NB, G3, GOUT);
    gru_layer<short><<<128, 512, 0, stream>>>(gxb, w_hh[1], b_ih[1], b_hh[1], hbuf, 1 * 1024, x1, nullptr, seq);
    gemm_bt<short><<<gg, 256, 0, stream>>>(x1, w2b, gxb, TT * NB, G3, GOUT);
    gru_layer<short><<<128, 512, 0, stream>>>(gxb, w_hh[2], b_ih[2], b_hh[2], hbuf, 2 * 1024, nullptr, (float*)d_out, seq);
  }
}